// Round 5
// baseline (359.778 us; speedup 1.0000x reference)
//
#include <hip/hip_runtime.h>
#include <hip/hip_bf16.h>

#define N_NODES 100000
#define N_EDGES 1600000
#define IN_FEAT 256
#define HID_F   128
#define OUT_FT  64

#define NBUK   256
#define NPB    391      // nodes per bucket: 256*391 = 100096 >= N
#define BUKCAP 8192     // mean 6250, sigma ~79 -> +24 sigma, safe
#define EPB    4096     // edges per bin block
#define G_BIN  ((N_EDGES + EPB - 1) / EPB)  // 391
#define G_GEMM ((N_NODES + 63) / 64)        // 1563, 64-row tiles
#define G_CAST ((IN_FEAT * HID_F + HID_F * OUT_FT + 255) / 256)  // 160
#define G_AGG  ((N_NODES + 7) / 8)          // 12500, 2 nodes per wave

typedef unsigned short u16;
typedef __attribute__((ext_vector_type(8))) unsigned short u16x8;
typedef __attribute__((ext_vector_type(8))) short short8;
typedef __attribute__((ext_vector_type(4))) float f32x4;

static __device__ inline u16 f2bf(float f) {
    __hip_bfloat16 h = __float2bfloat16(f);
    return *reinterpret_cast<u16*>(&h);
}
static __device__ inline float bf2f(u16 u) {
    union { unsigned u; float f; } c;
    c.u = ((unsigned)u) << 16;
    return c.f;
}

// ---------------- pass A: bin edges by dst bucket (+ weight cast piggyback) ----------------

__global__ __launch_bounds__(256) void k_bin(const int* __restrict__ srcA,
                                             const int* __restrict__ dstA,
                                             int* __restrict__ gcur, int2* __restrict__ pairs,
                                             const float* __restrict__ W1,
                                             const float* __restrict__ W2,
                                             u16* __restrict__ W1t, u16* __restrict__ W2t) {
    if (blockIdx.x >= G_BIN) {
        int idx = (blockIdx.x - G_BIN) * 256 + threadIdx.x;
        if (idx < IN_FEAT * HID_F) {
            int k = idx / HID_F, n = idx % HID_F;
            W1t[n * IN_FEAT + k] = f2bf(W1[idx]);
        } else {
            int e2 = idx - IN_FEAT * HID_F;
            if (e2 < HID_F * OUT_FT) {
                int k = e2 / OUT_FT, n = e2 % OUT_FT;
                W2t[n * HID_F + k] = f2bf(W2[e2]);
            }
        }
        return;
    }
    __shared__ int lh[NBUK];
    int t = threadIdx.x;
    int e0 = blockIdx.x * EPB;
    if (t < NBUK) lh[t] = 0;
    __syncthreads();
#pragma unroll
    for (int i = 0; i < EPB / 256; i++) {
        int e = e0 + i * 256 + t;
        if (e < N_EDGES) atomicAdd(&lh[dstA[e] / NPB], 1);
    }
    __syncthreads();
    if (t < NBUK) {
        int c = lh[t];
        lh[t] = atomicAdd(&gcur[t], c);  // becomes this block's base in bucket
    }
    __syncthreads();
#pragma unroll
    for (int i = 0; i < EPB / 256; i++) {
        int e = e0 + i * 256 + t;
        if (e < N_EDGES) {
            int d = dstA[e];
            int b = d / NPB;
            int p = atomicAdd(&lh[b], 1);
            if (p < BUKCAP) pairs[(size_t)b * BUKCAP + p] = make_int2(srcA[e], d);
        }
    }
}

// ---------------- pass B: per-bucket CSR fill + offsets + dinv (scan folded in) ----------------

__global__ __launch_bounds__(256) void k_fillB(const int2* __restrict__ pairs,
                                               const int* __restrict__ gcnt,
                                               int* __restrict__ offsets,
                                               float* __restrict__ dinv,
                                               int* __restrict__ csr) {
    __shared__ int hist[NPB];
    __shared__ int sm[256];
    __shared__ int s_ebase;
    int b = blockIdx.x, t = threadIdx.x;
    int nbase = b * NPB;
    int nn = min(NPB, N_NODES - nbase);

    // exclusive scan over bucket counts
    int gv = gcnt[t];
    sm[t] = gv;
    __syncthreads();
    for (int o = 1; o < 256; o <<= 1) {
        int u = (t >= o) ? sm[t - o] : 0;
        __syncthreads();
        sm[t] += u;
        __syncthreads();
    }
    if (t == b) s_ebase = sm[t] - gv;
    __syncthreads();
    int ebase = s_ebase;
    int cnt = gcnt[b];
    const int2* pb = pairs + (size_t)b * BUKCAP;

    for (int i = t; i < NPB; i += 256) hist[i] = 0;
    __syncthreads();
    for (int i = t; i < cnt; i += 256) atomicAdd(&hist[pb[i].y - nbase], 1);
    __syncthreads();

    // exclusive scan over hist[0..nn): thread t owns nodes [2t, 2t+2)
    int base2 = t * 2;
    int c0 = (base2 < NPB) ? hist[base2] : 0;
    int c1 = (base2 + 1 < NPB) ? hist[base2 + 1] : 0;
    int s = c0 + c1;
    __syncthreads();
    sm[t] = s;
    __syncthreads();
    for (int o = 1; o < 256; o <<= 1) {
        int u = (t >= o) ? sm[t - o] : 0;
        __syncthreads();
        sm[t] += u;
        __syncthreads();
    }
    int run = ebase + sm[t] - s;
    __syncthreads();
    int cc[2] = {c0, c1};
#pragma unroll
    for (int q = 0; q < 2; q++) {
        int n = base2 + q;
        if (n < nn) {
            int g = nbase + n;
            offsets[g] = run;
            dinv[g] = rsqrtf((float)(cc[q] + 1));  // +1 self loop
            hist[n] = run;                          // becomes placement cursor
            run += cc[q];
        }
    }
    __syncthreads();
    for (int i = t; i < cnt; i += 256) {
        int2 e = pb[i];
        int p = atomicAdd(&hist[e.y - nbase], 1);
        csr[p] = e.x;
    }
    if (b == NBUK - 1 && t == 0) offsets[N_NODES] = N_EDGES;
}

// ---------------- MFMA bf16 GEMM, layer 1 ----------------
// 64-row tiles (grid 1563), double-buffered LDS, ONE barrier per k-step,
// register prefetch of step s+1 issued before step s's barrier.

__global__ __launch_bounds__(256) void k_gemm1(const float* __restrict__ A,
                                               const u16* __restrict__ Bt,
                                               const float* __restrict__ dinv,
                                               u16* __restrict__ C) {
    __shared__ u16 As[2][64][40];    // 10240 B
    __shared__ u16 Bs[2][128][40];   // 20480 B
    int tid = threadIdx.x;
    int wv = tid >> 6, lane = tid & 63;
    int m16 = lane & 15, quad = lane >> 4;
    int row0 = blockIdx.x * 64;

    int ar = tid >> 2, aq = tid & 3;
    int br = tid >> 1, bh = tid & 1;
    int arow_g = row0 + ar;
    if (arow_g >= N_NODES) arow_g = N_NODES - 1;   // clamp, stores guarded
    const float* ap = &A[(size_t)arow_g * IN_FEAT + aq * 8];
    const u16*   bp = &Bt[(size_t)br * IN_FEAT + bh * 16];

    f32x4 acc[8];
#pragma unroll
    for (int j = 0; j < 8; j++) acc[j] = (f32x4)(0.f);

    {
        f32x4 a0 = *(const f32x4*)&ap[0];
        f32x4 a1 = *(const f32x4*)&ap[4];
        u16x8 b0 = *(const u16x8*)&bp[0];
        u16x8 b1 = *(const u16x8*)&bp[8];
        u16x8 av;
#pragma unroll
        for (int j = 0; j < 4; j++) { av[j] = f2bf(a0[j]); av[4 + j] = f2bf(a1[j]); }
        *(u16x8*)&As[0][ar][aq * 8] = av;
        *(u16x8*)&Bs[0][br][bh * 16] = b0;
        *(u16x8*)&Bs[0][br][bh * 16 + 8] = b1;
    }

#pragma unroll
    for (int s = 0; s < 8; s++) {
        const int buf = s & 1;
        f32x4 na0, na1; u16x8 nb0, nb1;
        if (s + 1 < 8) {
            int k0 = (s + 1) * 32;
            na0 = *(const f32x4*)&ap[k0];
            na1 = *(const f32x4*)&ap[k0 + 4];
            nb0 = *(const u16x8*)&bp[k0];
            nb1 = *(const u16x8*)&bp[k0 + 8];
        }
        __syncthreads();   // buf ready (written before this barrier)
        short8 af = *(const short8*)&As[buf][wv * 16 + m16][quad * 8];
#pragma unroll
        for (int ct = 0; ct < 8; ct++) {
            short8 bf = *(const short8*)&Bs[buf][16 * ct + m16][quad * 8];
            acc[ct] = __builtin_amdgcn_mfma_f32_16x16x32_bf16(af, bf, acc[ct], 0, 0, 0);
        }
        if (s + 1 < 8) {
            u16x8 av;
#pragma unroll
            for (int j = 0; j < 4; j++) { av[j] = f2bf(na0[j]); av[4 + j] = f2bf(na1[j]); }
            *(u16x8*)&As[buf ^ 1][ar][aq * 8] = av;
            *(u16x8*)&Bs[buf ^ 1][br][bh * 16] = nb0;
            *(u16x8*)&Bs[buf ^ 1][br][bh * 16 + 8] = nb1;
        }
    }

#pragma unroll
    for (int r4 = 0; r4 < 4; r4++) {
        int grow = row0 + wv * 16 + quad * 4 + r4;
        if (grow < N_NODES) {
            float dv = dinv[grow];
#pragma unroll
            for (int ct = 0; ct < 8; ct++)
                C[(size_t)grow * HID_F + 16 * ct + m16] = f2bf(acc[ct][r4] * dv);
        }
    }
}

// ---------------- FUSED: aggregation layer 1 + GEMM layer 2 ----------------
// One block owns 64 nodes. Phase A: gather-aggregate hs1 neighbors (2 nodes/wave,
// 8 sweeps), write ReLU'd a1 rows to LDS (k-chunked [4][65][40], bank-safe).
// Phase B: MFMA from LDS; B-fragments straight from 16KB L1-hot W2t. hs2 must
// NOT alias hs1 (cross-block gathers still read hs1).

__global__ __launch_bounds__(256) void k_agg1gemm2(const u16* __restrict__ hs,
                                                   const int* __restrict__ offsets,
                                                   const int* __restrict__ csr,
                                                   const float* __restrict__ dinv,
                                                   const float* __restrict__ b1v,
                                                   const u16* __restrict__ W2t,
                                                   u16* __restrict__ hs2) {
    __shared__ u16 As[4][65][40];   // 20800 B; chunk stride 65 breaks c-collapse
    int t = threadIdx.x;
    int wave = t >> 6;
    int lane = t & 63;
    int half = lane >> 5;
    int row0 = blockIdx.x * 64;

    int gl = lane & 31;
    int g = gl >> 4;          // edge slot 0..1 within this node's half-wave
    int fl = gl & 15;         // feature-block lane
    const int fo = fl * 8;    // 8 features per lane

    // ---- phase A: aggregate 64 nodes, 8 sweeps of (2 nodes/wave × 4 waves) ----
#pragma unroll 1
    for (int sweep = 0; sweep < 8; sweep++) {
        int nl = sweep * 8 + wave * 2 + half;   // node-local 0..63
        int node = row0 + nl;
        if (node < N_NODES) {
            int beg = offsets[node], end = offsets[node + 1];

            float accA[8], accB[8];
#pragma unroll
            for (int i = 0; i < 8; i++) { accA[i] = 0.f; accB[i] = 0.f; }

            int j = beg;
            for (; j + 8 <= end; j += 8) {  // 8 edges, 4 gathers in flight per lane
                int s0 = csr[j + g];
                int s1 = csr[j + 2 + g];
                int s2 = csr[j + 4 + g];
                int s3 = csr[j + 6 + g];
                u16x8 r0 = *(const u16x8*)&hs[(size_t)s0 * HID_F + fo];
                u16x8 r1 = *(const u16x8*)&hs[(size_t)s1 * HID_F + fo];
                u16x8 r2 = *(const u16x8*)&hs[(size_t)s2 * HID_F + fo];
                u16x8 r3 = *(const u16x8*)&hs[(size_t)s3 * HID_F + fo];
#pragma unroll
                for (int i = 0; i < 8; i++) {
                    accA[i] += bf2f(r0[i]) + bf2f(r1[i]);
                    accB[i] += bf2f(r2[i]) + bf2f(r3[i]);
                }
            }
            if (j + 4 <= end) {
                int s0 = csr[j + g];
                int s1 = csr[j + 2 + g];
                u16x8 r0 = *(const u16x8*)&hs[(size_t)s0 * HID_F + fo];
                u16x8 r1 = *(const u16x8*)&hs[(size_t)s1 * HID_F + fo];
#pragma unroll
                for (int i = 0; i < 8; i++) accA[i] += bf2f(r0[i]) + bf2f(r1[i]);
                j += 4;
            }
            for (; j < end; j += 2) {
                int idx = j + g;
                if (idx < end) {
                    int s = csr[idx];
                    u16x8 r0 = *(const u16x8*)&hs[(size_t)s * HID_F + fo];
#pragma unroll
                    for (int i = 0; i < 8; i++) accB[i] += bf2f(r0[i]);
                }
            }
#pragma unroll
            for (int i = 0; i < 8; i++) {
                float v = accA[i] + accB[i];
                v += __shfl_xor(v, 16, 64);
                accA[i] = v;
            }
            if (g == 0) {
                u16x8 sr = *(const u16x8*)&hs[(size_t)node * HID_F + fo];
                float dv = dinv[node];
                f32x4 b0 = *(const f32x4*)&b1v[fo];
                f32x4 b1q = *(const f32x4*)&b1v[fo + 4];
                u16x8 o;
#pragma unroll
                for (int i = 0; i < 4; i++) {
                    o[i]     = f2bf(fmaxf(dv * (accA[i]     + bf2f(sr[i]))     + b0[i], 0.f));
                    o[4 + i] = f2bf(fmaxf(dv * (accA[4 + i] + bf2f(sr[4 + i])) + b1q[i], 0.f));
                }
                int c = fo >> 5;          // k-chunk 0..3
                int off = fo & 31;        // 0,8,16,24
                *(u16x8*)&As[c][nl][off] = o;
            }
        }
    }
    __syncthreads();

    // ---- phase B: gemm2 from LDS (rows) x W2t (global, L1-hot) ----
    int wv = wave, m16 = lane & 15, quad = lane >> 4;
    f32x4 acc[4];
#pragma unroll
    for (int j = 0; j < 4; j++) acc[j] = (f32x4)(0.f);

#pragma unroll
    for (int s = 0; s < 4; s++) {
        short8 af = *(const short8*)&As[s][wv * 16 + m16][quad * 8];
#pragma unroll
        for (int ct = 0; ct < 4; ct++) {
            short8 bf = *(const short8*)&W2t[(size_t)(16 * ct + m16) * HID_F + s * 32 + quad * 8];
            acc[ct] = __builtin_amdgcn_mfma_f32_16x16x32_bf16(af, bf, acc[ct], 0, 0, 0);
        }
    }

#pragma unroll
    for (int r4 = 0; r4 < 4; r4++) {
        int grow = row0 + wv * 16 + quad * 4 + r4;
        if (grow < N_NODES) {
            float dv = dinv[grow];
#pragma unroll
            for (int ct = 0; ct < 4; ct++)
                hs2[(size_t)grow * OUT_FT + 16 * ct + m16] = f2bf(acc[ct][r4] * dv);
        }
    }
}

// ---------------- agg2: 2 nodes per wave; 8 lanes x 16B cover a 128B row ----------------

__global__ __launch_bounds__(256) void k_agg2(const u16* __restrict__ hs,
                                              const int* __restrict__ offsets,
                                              const int* __restrict__ csr,
                                              const float* __restrict__ dinv,
                                              const float* __restrict__ b,
                                              float* __restrict__ out) {
    int wave = threadIdx.x >> 6;
    int lane = threadIdx.x & 63;
    int half = lane >> 5;
    int node = blockIdx.x * 8 + wave * 2 + half;
    if (node >= N_NODES) return;
    int gl = lane & 31;
    int g = gl >> 3;          // edge slot 0..3 within this node's half-wave
    int fl = gl & 7;          // feature-block lane
    const int fo = fl * 8;
    int beg = offsets[node], end = offsets[node + 1];

    float accA[8], accB[8];
#pragma unroll
    for (int i = 0; i < 8; i++) { accA[i] = 0.f; accB[i] = 0.f; }

    int j = beg;
    for (; j + 16 <= end; j += 16) {  // 16 edges, 4 gathers in flight per lane
        int s0 = csr[j + g];
        int s1 = csr[j + 4 + g];
        int s2 = csr[j + 8 + g];
        int s3 = csr[j + 12 + g];
        u16x8 r0 = *(const u16x8*)&hs[(size_t)s0 * OUT_FT + fo];
        u16x8 r1 = *(const u16x8*)&hs[(size_t)s1 * OUT_FT + fo];
        u16x8 r2 = *(const u16x8*)&hs[(size_t)s2 * OUT_FT + fo];
        u16x8 r3 = *(const u16x8*)&hs[(size_t)s3 * OUT_FT + fo];
#pragma unroll
        for (int i = 0; i < 8; i++) {
            accA[i] += bf2f(r0[i]) + bf2f(r1[i]);
            accB[i] += bf2f(r2[i]) + bf2f(r3[i]);
        }
    }
    if (j + 8 <= end) {
        int s0 = csr[j + g];
        int s1 = csr[j + 4 + g];
        u16x8 r0 = *(const u16x8*)&hs[(size_t)s0 * OUT_FT + fo];
        u16x8 r1 = *(const u16x8*)&hs[(size_t)s1 * OUT_FT + fo];
#pragma unroll
        for (int i = 0; i < 8; i++) accA[i] += bf2f(r0[i]) + bf2f(r1[i]);
        j += 8;
    }
    for (; j < end; j += 4) {
        int idx = j + g;
        if (idx < end) {
            int s = csr[idx];
            u16x8 r0 = *(const u16x8*)&hs[(size_t)s * OUT_FT + fo];
#pragma unroll
            for (int i = 0; i < 8; i++) accB[i] += bf2f(r0[i]);
        }
    }
#pragma unroll
    for (int i = 0; i < 8; i++) {
        float v = accA[i] + accB[i];
        v += __shfl_xor(v, 8, 64);
        v += __shfl_xor(v, 16, 64);
        accA[i] = v;
    }
    if (g == 0) {
        u16x8 sr = *(const u16x8*)&hs[(size_t)node * OUT_FT + fo];
        float dv = dinv[node];
        f32x4 b0 = *(const f32x4*)&b[fo];
        f32x4 b1 = *(const f32x4*)&b[fo + 4];
        f32x4 o0, o1;
#pragma unroll
        for (int i = 0; i < 4; i++) {
            o0[i] = dv * (accA[i]     + bf2f(sr[i]))     + b0[i];
            o1[i] = dv * (accA[4 + i] + bf2f(sr[4 + i])) + b1[i];
        }
        *(f32x4*)&out[(size_t)node * OUT_FT + fo] = o0;
        *(f32x4*)&out[(size_t)node * OUT_FT + fo + 4] = o1;
    }
}

// ---------------- launch ----------------

extern "C" void kernel_launch(void* const* d_in, const int* in_sizes, int n_in,
                              void* d_out, int out_size, void* d_ws, size_t ws_size,
                              hipStream_t stream) {
    const float* x  = (const float*)d_in[0];
    const int*   ei = (const int*)d_in[1];  // [2][E]
    const float* W1 = (const float*)d_in[2];
    const float* b1 = (const float*)d_in[3];
    const float* W2 = (const float*)d_in[4];
    const float* b2 = (const float*)d_in[5];
    float* out = (float*)d_out;

    char* ws = (char*)d_ws;
    int*   offsets = (int*)(ws + 0);          // (N+1) ints -> 400512
    float* dinv    = (float*)(ws + 400512);   // N floats   -> 800512
    int*   csr     = (int*)(ws + 800512);     // E ints     -> 7200512
    u16*   W1t     = (u16*)(ws + 7200512);    // 128x256    -> 7266048
    u16*   W2t     = (u16*)(ws + 7266048);    // 64x128     -> 7282432
    int*   gcur    = (int*)(ws + 7282432);    // 256 ints   -> 7283456
    u16*   hs1     = (u16*)(ws + 7284608);    // N*128 bf16 -> 32884608
    u16*   hs2     = (u16*)(ws + 32884608);   // N*64  bf16 (12.8MB) — must NOT alias hs1
    int2*  pairs   = (int2*)(ws + 32884608);  // 16.78 MB, dead after fillB (before hs2 written)

    const int* srcA = ei;
    const int* dstA = ei + N_EDGES;

    hipMemsetAsync(gcur, 0, NBUK * sizeof(int), stream);

    k_bin<<<G_BIN + G_CAST, 256, 0, stream>>>(srcA, dstA, gcur, pairs, W1, W2, W1t, W2t);
    k_fillB<<<NBUK, 256, 0, stream>>>(pairs, gcur, offsets, dinv, csr);

    k_gemm1<<<G_GEMM, 256, 0, stream>>>(x, W1t, dinv, hs1);
    k_agg1gemm2<<<G_GEMM, 256, 0, stream>>>(hs1, offsets, csr, dinv, b1, W2t, hs2);
    k_agg2<<<G_AGG, 256, 0, stream>>>(hs2, offsets, csr, dinv, b2, out);
}

// Round 6
// 335.528 us; speedup vs baseline: 1.0723x; 1.0723x over previous
//
#include <hip/hip_runtime.h>
#include <hip/hip_bf16.h>

#define N_NODES 100000
#define N_EDGES 1600000
#define IN_FEAT 256
#define HID_F   128
#define OUT_FT  64

#define NBUK   256
#define NPB    391      // nodes per bucket: 256*391 = 100096 >= N
#define BUKCAP 8192     // mean 6250, sigma ~79 -> +24 sigma, safe
#define EPB    4096     // edges per bin block
#define G_BIN  ((N_EDGES + EPB - 1) / EPB)  // 391
#define G_GEMM ((N_NODES + 63) / 64)        // 1563, 64-row tiles
#define G_CAST ((IN_FEAT * HID_F + HID_F * OUT_FT + 255) / 256)  // 160
#define G_AGG  ((N_NODES + 7) / 8)          // 12500, 2 nodes per wave

typedef unsigned short u16;
typedef __attribute__((ext_vector_type(8))) unsigned short u16x8;
typedef __attribute__((ext_vector_type(8))) short short8;
typedef __attribute__((ext_vector_type(4))) float f32x4;

static __device__ inline u16 f2bf(float f) {
    __hip_bfloat16 h = __float2bfloat16(f);
    return *reinterpret_cast<u16*>(&h);
}
static __device__ inline float bf2f(u16 u) {
    union { unsigned u; float f; } c;
    c.u = ((unsigned)u) << 16;
    return c.f;
}

// ---------------- pass A: bin edges by dst bucket (+ weight cast piggyback) ----------------
// pairs entry is PACKED: (dstLocal << 17) | src   (dstLocal < 391 < 2^9, src < 100000 < 2^17)
// 4B scattered stores instead of 8B halves the write-allocate traffic.

__global__ __launch_bounds__(256) void k_bin(const int* __restrict__ srcA,
                                             const int* __restrict__ dstA,
                                             int* __restrict__ gcur, unsigned* __restrict__ pairs,
                                             const float* __restrict__ W1,
                                             const float* __restrict__ W2,
                                             u16* __restrict__ W1t, u16* __restrict__ W2t) {
    if (blockIdx.x >= G_BIN) {
        int idx = (blockIdx.x - G_BIN) * 256 + threadIdx.x;
        if (idx < IN_FEAT * HID_F) {
            int k = idx / HID_F, n = idx % HID_F;
            W1t[n * IN_FEAT + k] = f2bf(W1[idx]);
        } else {
            int e2 = idx - IN_FEAT * HID_F;
            if (e2 < HID_F * OUT_FT) {
                int k = e2 / OUT_FT, n = e2 % OUT_FT;
                W2t[n * HID_F + k] = f2bf(W2[e2]);
            }
        }
        return;
    }
    __shared__ int lh[NBUK];
    int t = threadIdx.x;
    int e0 = blockIdx.x * EPB;
    if (t < NBUK) lh[t] = 0;
    __syncthreads();
#pragma unroll
    for (int i = 0; i < EPB / 256; i++) {
        int e = e0 + i * 256 + t;
        if (e < N_EDGES) atomicAdd(&lh[dstA[e] / NPB], 1);
    }
    __syncthreads();
    if (t < NBUK) {
        int c = lh[t];
        lh[t] = atomicAdd(&gcur[t], c);  // becomes this block's base in bucket
    }
    __syncthreads();
#pragma unroll
    for (int i = 0; i < EPB / 256; i++) {
        int e = e0 + i * 256 + t;
        if (e < N_EDGES) {
            int d = dstA[e];
            int b = d / NPB;
            int p = atomicAdd(&lh[b], 1);
            if (p < BUKCAP) {
                unsigned packed = ((unsigned)(d - b * NPB) << 17) | (unsigned)srcA[e];
                pairs[(size_t)b * BUKCAP + p] = packed;
            }
        }
    }
}

// ---------------- pass B: per-bucket CSR fill + offsets + dinv (scan folded in) ----------------

__global__ __launch_bounds__(256) void k_fillB(const unsigned* __restrict__ pairs,
                                               const int* __restrict__ gcnt,
                                               int* __restrict__ offsets,
                                               float* __restrict__ dinv,
                                               int* __restrict__ csr) {
    __shared__ int hist[NPB];
    __shared__ int sm[256];
    __shared__ int s_ebase;
    int b = blockIdx.x, t = threadIdx.x;
    int nbase = b * NPB;
    int nn = min(NPB, N_NODES - nbase);

    // exclusive scan over bucket counts
    int gv = gcnt[t];
    sm[t] = gv;
    __syncthreads();
    for (int o = 1; o < 256; o <<= 1) {
        int u = (t >= o) ? sm[t - o] : 0;
        __syncthreads();
        sm[t] += u;
        __syncthreads();
    }
    if (t == b) s_ebase = sm[t] - gv;
    __syncthreads();
    int ebase = s_ebase;
    int cnt = gcnt[b];
    const unsigned* pb = pairs + (size_t)b * BUKCAP;

    for (int i = t; i < NPB; i += 256) hist[i] = 0;
    __syncthreads();
    for (int i = t; i < cnt; i += 256) atomicAdd(&hist[pb[i] >> 17], 1);
    __syncthreads();

    // exclusive scan over hist[0..nn): thread t owns nodes [2t, 2t+2)
    int base2 = t * 2;
    int c0 = (base2 < NPB) ? hist[base2] : 0;
    int c1 = (base2 + 1 < NPB) ? hist[base2 + 1] : 0;
    int s = c0 + c1;
    __syncthreads();
    sm[t] = s;
    __syncthreads();
    for (int o = 1; o < 256; o <<= 1) {
        int u = (t >= o) ? sm[t - o] : 0;
        __syncthreads();
        sm[t] += u;
        __syncthreads();
    }
    int run = ebase + sm[t] - s;
    __syncthreads();
    int cc[2] = {c0, c1};
#pragma unroll
    for (int q = 0; q < 2; q++) {
        int n = base2 + q;
        if (n < nn) {
            int g = nbase + n;
            offsets[g] = run;
            dinv[g] = rsqrtf((float)(cc[q] + 1));  // +1 self loop
            hist[n] = run;                          // becomes placement cursor
            run += cc[q];
        }
    }
    __syncthreads();
    for (int i = t; i < cnt; i += 256) {
        unsigned e = pb[i];
        int p = atomicAdd(&hist[e >> 17], 1);
        csr[p] = (int)(e & 0x1FFFFu);
    }
    if (b == NBUK - 1 && t == 0) offsets[N_NODES] = N_EDGES;
}

// ---------------- MFMA bf16 GEMM, layer 1 ----------------
// 64-row tiles (grid 1563), double-buffered LDS, ONE barrier per k-step,
// register prefetch of step s+1 issued before step s's barrier.

__global__ __launch_bounds__(256) void k_gemm1(const float* __restrict__ A,
                                               const u16* __restrict__ Bt,
                                               const float* __restrict__ dinv,
                                               u16* __restrict__ C) {
    __shared__ u16 As[2][64][40];    // 10240 B
    __shared__ u16 Bs[2][128][40];   // 20480 B
    int tid = threadIdx.x;
    int wv = tid >> 6, lane = tid & 63;
    int m16 = lane & 15, quad = lane >> 4;
    int row0 = blockIdx.x * 64;

    int ar = tid >> 2, aq = tid & 3;
    int br = tid >> 1, bh = tid & 1;
    int arow_g = row0 + ar;
    if (arow_g >= N_NODES) arow_g = N_NODES - 1;   // clamp, stores guarded
    const float* ap = &A[(size_t)arow_g * IN_FEAT + aq * 8];
    const u16*   bp = &Bt[(size_t)br * IN_FEAT + bh * 16];

    f32x4 acc[8];
#pragma unroll
    for (int j = 0; j < 8; j++) acc[j] = (f32x4)(0.f);

    {
        f32x4 a0 = *(const f32x4*)&ap[0];
        f32x4 a1 = *(const f32x4*)&ap[4];
        u16x8 b0 = *(const u16x8*)&bp[0];
        u16x8 b1 = *(const u16x8*)&bp[8];
        u16x8 av;
#pragma unroll
        for (int j = 0; j < 4; j++) { av[j] = f2bf(a0[j]); av[4 + j] = f2bf(a1[j]); }
        *(u16x8*)&As[0][ar][aq * 8] = av;
        *(u16x8*)&Bs[0][br][bh * 16] = b0;
        *(u16x8*)&Bs[0][br][bh * 16 + 8] = b1;
    }

#pragma unroll
    for (int s = 0; s < 8; s++) {
        const int buf = s & 1;
        f32x4 na0, na1; u16x8 nb0, nb1;
        if (s + 1 < 8) {
            int k0 = (s + 1) * 32;
            na0 = *(const f32x4*)&ap[k0];
            na1 = *(const f32x4*)&ap[k0 + 4];
            nb0 = *(const u16x8*)&bp[k0];
            nb1 = *(const u16x8*)&bp[k0 + 8];
        }
        __syncthreads();   // buf ready (written before this barrier)
        short8 af = *(const short8*)&As[buf][wv * 16 + m16][quad * 8];
#pragma unroll
        for (int ct = 0; ct < 8; ct++) {
            short8 bf = *(const short8*)&Bs[buf][16 * ct + m16][quad * 8];
            acc[ct] = __builtin_amdgcn_mfma_f32_16x16x32_bf16(af, bf, acc[ct], 0, 0, 0);
        }
        if (s + 1 < 8) {
            u16x8 av;
#pragma unroll
            for (int j = 0; j < 4; j++) { av[j] = f2bf(na0[j]); av[4 + j] = f2bf(na1[j]); }
            *(u16x8*)&As[buf ^ 1][ar][aq * 8] = av;
            *(u16x8*)&Bs[buf ^ 1][br][bh * 16] = nb0;
            *(u16x8*)&Bs[buf ^ 1][br][bh * 16 + 8] = nb1;
        }
    }

#pragma unroll
    for (int r4 = 0; r4 < 4; r4++) {
        int grow = row0 + wv * 16 + quad * 4 + r4;
        if (grow < N_NODES) {
            float dv = dinv[grow];
#pragma unroll
            for (int ct = 0; ct < 8; ct++)
                C[(size_t)grow * HID_F + 16 * ct + m16] = f2bf(acc[ct][r4] * dv);
        }
    }
}

// ---------------- MFMA bf16 GEMM, layer 2 ----------------
// Same structure: 64-row tiles, dbuf LDS, 1 barrier/step, reg prefetch. K=128.

__global__ __launch_bounds__(256) void k_gemm2(const u16* __restrict__ A,
                                               const u16* __restrict__ Bt,
                                               const float* __restrict__ dinv,
                                               u16* __restrict__ C) {
    __shared__ u16 As[2][64][40];   // 10240 B
    __shared__ u16 Bs[2][64][40];   // 10240 B
    int tid = threadIdx.x;
    int wv = tid >> 6, lane = tid & 63;
    int m16 = lane & 15, quad = lane >> 4;
    int row0 = blockIdx.x * 64;

    int ar = tid >> 2, aq = tid & 3;   // A: row 0..63, 8-elem quarter
    int arow_g = row0 + ar;
    if (arow_g >= N_NODES) arow_g = N_NODES - 1;
    const u16* ap = &A[(size_t)arow_g * HID_F + aq * 8];
    const u16* bp = &Bt[(size_t)ar * HID_F + aq * 8];  // B: row 0..63, same quarter split

    f32x4 acc[4];
#pragma unroll
    for (int j = 0; j < 4; j++) acc[j] = (f32x4)(0.f);

    {
        u16x8 a0 = *(const u16x8*)&ap[0];
        u16x8 b0 = *(const u16x8*)&bp[0];
        *(u16x8*)&As[0][ar][aq * 8] = a0;
        *(u16x8*)&Bs[0][ar][aq * 8] = b0;
    }

#pragma unroll
    for (int s = 0; s < 4; s++) {
        const int buf = s & 1;
        u16x8 na, nb;
        if (s + 1 < 4) {
            int k0 = (s + 1) * 32;
            na = *(const u16x8*)&ap[k0];
            nb = *(const u16x8*)&bp[k0];
        }
        __syncthreads();
        short8 af = *(const short8*)&As[buf][wv * 16 + m16][quad * 8];
#pragma unroll
        for (int ct = 0; ct < 4; ct++) {
            short8 bf = *(const short8*)&Bs[buf][16 * ct + m16][quad * 8];
            acc[ct] = __builtin_amdgcn_mfma_f32_16x16x32_bf16(af, bf, acc[ct], 0, 0, 0);
        }
        if (s + 1 < 4) {
            *(u16x8*)&As[buf ^ 1][ar][aq * 8] = na;
            *(u16x8*)&Bs[buf ^ 1][ar][aq * 8] = nb;
        }
    }

#pragma unroll
    for (int r4 = 0; r4 < 4; r4++) {
        int grow = row0 + wv * 16 + quad * 4 + r4;
        if (grow < N_NODES) {
            float dv = dinv[grow];
#pragma unroll
            for (int ct = 0; ct < 4; ct++)
                C[(size_t)grow * OUT_FT + 16 * ct + m16] = f2bf(acc[ct][r4] * dv);
        }
    }
}

// ---------------- aggregation: wide-gather CSR reduce ----------------
// agg1: 2 nodes per wave (half-wave each); 16 lanes x 16B cover a 256B row;
// main loop keeps 4 gathers in flight per lane (8 edges/node/iter).

__global__ __launch_bounds__(256) void k_agg1(const u16* __restrict__ hs,
                                              const int* __restrict__ offsets,
                                              const int* __restrict__ csr,
                                              const float* __restrict__ dinv,
                                              const float* __restrict__ b,
                                              u16* __restrict__ out) {
    int wave = threadIdx.x >> 6;
    int lane = threadIdx.x & 63;
    int half = lane >> 5;
    int node = blockIdx.x * 8 + wave * 2 + half;
    if (node >= N_NODES) return;
    int gl = lane & 31;
    int g = gl >> 4;          // edge slot 0..1 within this node's half-wave
    int fl = gl & 15;         // feature-block lane
    const int fo = fl * 8;    // 8 features per lane
    int beg = offsets[node], end = offsets[node + 1];

    float accA[8], accB[8];
#pragma unroll
    for (int i = 0; i < 8; i++) { accA[i] = 0.f; accB[i] = 0.f; }

    int j = beg;
    for (; j + 8 <= end; j += 8) {  // 8 edges, 4 gather loads in flight per lane
        int s0 = csr[j + g];
        int s1 = csr[j + 2 + g];
        int s2 = csr[j + 4 + g];
        int s3 = csr[j + 6 + g];
        u16x8 r0 = *(const u16x8*)&hs[(size_t)s0 * HID_F + fo];
        u16x8 r1 = *(const u16x8*)&hs[(size_t)s1 * HID_F + fo];
        u16x8 r2 = *(const u16x8*)&hs[(size_t)s2 * HID_F + fo];
        u16x8 r3 = *(const u16x8*)&hs[(size_t)s3 * HID_F + fo];
#pragma unroll
        for (int i = 0; i < 8; i++) {
            accA[i] += bf2f(r0[i]) + bf2f(r1[i]);
            accB[i] += bf2f(r2[i]) + bf2f(r3[i]);
        }
    }
    if (j + 4 <= end) {
        int s0 = csr[j + g];
        int s1 = csr[j + 2 + g];
        u16x8 r0 = *(const u16x8*)&hs[(size_t)s0 * HID_F + fo];
        u16x8 r1 = *(const u16x8*)&hs[(size_t)s1 * HID_F + fo];
#pragma unroll
        for (int i = 0; i < 8; i++) accA[i] += bf2f(r0[i]) + bf2f(r1[i]);
        j += 4;
    }
    for (; j < end; j += 2) {
        int idx = j + g;
        if (idx < end) {
            int s = csr[idx];
            u16x8 r0 = *(const u16x8*)&hs[(size_t)s * HID_F + fo];
#pragma unroll
            for (int i = 0; i < 8; i++) accB[i] += bf2f(r0[i]);
        }
    }
    // reduce the 2 edge slots (stays within this node's 32-lane half)
#pragma unroll
    for (int i = 0; i < 8; i++) {
        float v = accA[i] + accB[i];
        v += __shfl_xor(v, 16, 64);
        accA[i] = v;
    }
    if (g == 0) {
        u16x8 sr = *(const u16x8*)&hs[(size_t)node * HID_F + fo];
        float dv = dinv[node];
        f32x4 b0 = *(const f32x4*)&b[fo];
        f32x4 b1 = *(const f32x4*)&b[fo + 4];
        u16x8 o;
#pragma unroll
        for (int i = 0; i < 4; i++) {
            o[i]     = f2bf(fmaxf(dv * (accA[i]     + bf2f(sr[i]))     + b0[i], 0.f));
            o[4 + i] = f2bf(fmaxf(dv * (accA[4 + i] + bf2f(sr[4 + i])) + b1[i], 0.f));
        }
        *(u16x8*)&out[(size_t)node * HID_F + fo] = o;
    }
}

// agg2: 2 nodes per wave; 8 lanes x 16B cover a 128B row;
// main loop keeps 4 gathers in flight per lane (16 edges/node/iter); fp32 out.

__global__ __launch_bounds__(256) void k_agg2(const u16* __restrict__ hs,
                                              const int* __restrict__ offsets,
                                              const int* __restrict__ csr,
                                              const float* __restrict__ dinv,
                                              const float* __restrict__ b,
                                              float* __restrict__ out) {
    int wave = threadIdx.x >> 6;
    int lane = threadIdx.x & 63;
    int half = lane >> 5;
    int node = blockIdx.x * 8 + wave * 2 + half;
    if (node >= N_NODES) return;
    int gl = lane & 31;
    int g = gl >> 3;          // edge slot 0..3 within this node's half-wave
    int fl = gl & 7;          // feature-block lane
    const int fo = fl * 8;
    int beg = offsets[node], end = offsets[node + 1];

    float accA[8], accB[8];
#pragma unroll
    for (int i = 0; i < 8; i++) { accA[i] = 0.f; accB[i] = 0.f; }

    int j = beg;
    for (; j + 16 <= end; j += 16) {  // 16 edges, 4 gathers in flight per lane
        int s0 = csr[j + g];
        int s1 = csr[j + 4 + g];
        int s2 = csr[j + 8 + g];
        int s3 = csr[j + 12 + g];
        u16x8 r0 = *(const u16x8*)&hs[(size_t)s0 * OUT_FT + fo];
        u16x8 r1 = *(const u16x8*)&hs[(size_t)s1 * OUT_FT + fo];
        u16x8 r2 = *(const u16x8*)&hs[(size_t)s2 * OUT_FT + fo];
        u16x8 r3 = *(const u16x8*)&hs[(size_t)s3 * OUT_FT + fo];
#pragma unroll
        for (int i = 0; i < 8; i++) {
            accA[i] += bf2f(r0[i]) + bf2f(r1[i]);
            accB[i] += bf2f(r2[i]) + bf2f(r3[i]);
        }
    }
    if (j + 8 <= end) {
        int s0 = csr[j + g];
        int s1 = csr[j + 4 + g];
        u16x8 r0 = *(const u16x8*)&hs[(size_t)s0 * OUT_FT + fo];
        u16x8 r1 = *(const u16x8*)&hs[(size_t)s1 * OUT_FT + fo];
#pragma unroll
        for (int i = 0; i < 8; i++) accA[i] += bf2f(r0[i]) + bf2f(r1[i]);
        j += 8;
    }
    for (; j < end; j += 4) {
        int idx = j + g;
        if (idx < end) {
            int s = csr[idx];
            u16x8 r0 = *(const u16x8*)&hs[(size_t)s * OUT_FT + fo];
#pragma unroll
            for (int i = 0; i < 8; i++) accB[i] += bf2f(r0[i]);
        }
    }
#pragma unroll
    for (int i = 0; i < 8; i++) {
        float v = accA[i] + accB[i];
        v += __shfl_xor(v, 8, 64);
        v += __shfl_xor(v, 16, 64);
        accA[i] = v;
    }
    if (g == 0) {
        u16x8 sr = *(const u16x8*)&hs[(size_t)node * OUT_FT + fo];
        float dv = dinv[node];
        f32x4 b0 = *(const f32x4*)&b[fo];
        f32x4 b1 = *(const f32x4*)&b[fo + 4];
        f32x4 o0, o1;
#pragma unroll
        for (int i = 0; i < 4; i++) {
            o0[i] = dv * (accA[i]     + bf2f(sr[i]))     + b0[i];
            o1[i] = dv * (accA[4 + i] + bf2f(sr[4 + i])) + b1[i];
        }
        *(f32x4*)&out[(size_t)node * OUT_FT + fo] = o0;
        *(f32x4*)&out[(size_t)node * OUT_FT + fo + 4] = o1;
    }
}

// ---------------- launch ----------------

extern "C" void kernel_launch(void* const* d_in, const int* in_sizes, int n_in,
                              void* d_out, int out_size, void* d_ws, size_t ws_size,
                              hipStream_t stream) {
    const float* x  = (const float*)d_in[0];
    const int*   ei = (const int*)d_in[1];  // [2][E]
    const float* W1 = (const float*)d_in[2];
    const float* b1 = (const float*)d_in[3];
    const float* W2 = (const float*)d_in[4];
    const float* b2 = (const float*)d_in[5];
    float* out = (float*)d_out;

    char* ws = (char*)d_ws;
    int*   offsets = (int*)(ws + 0);          // (N+1) ints -> 400512
    float* dinv    = (float*)(ws + 400512);   // N floats   -> 800512
    int*   csr     = (int*)(ws + 800512);     // E ints     -> 7200512
    u16*   W1t     = (u16*)(ws + 7200512);    // 128x256    -> 7266048
    u16*   W2t     = (u16*)(ws + 7266048);    // 64x128     -> 7282432
    int*   gcur    = (int*)(ws + 7282432);    // 256 ints   -> 7283456
    u16*   hs1     = (u16*)(ws + 7284608);    // N*128 bf16 -> 32884608
    u16*   a1      = (u16*)(ws + 32884608);   // N*128 bf16 -> 58484608
    unsigned* pairs = (unsigned*)(ws + 32884608); // 8 MB packed, dead before agg1 writes a1
    u16*   hs2     = hs1;                     // hs1 dead after agg1

    const int* srcA = ei;
    const int* dstA = ei + N_EDGES;

    hipMemsetAsync(gcur, 0, NBUK * sizeof(int), stream);

    k_bin<<<G_BIN + G_CAST, 256, 0, stream>>>(srcA, dstA, gcur, pairs, W1, W2, W1t, W2t);
    k_fillB<<<NBUK, 256, 0, stream>>>(pairs, gcur, offsets, dinv, csr);

    k_gemm1<<<G_GEMM, 256, 0, stream>>>(x, W1t, dinv, hs1);
    k_agg1<<<G_AGG, 256, 0, stream>>>(hs1, offsets, csr, dinv, b1, a1);
    k_gemm2<<<G_GEMM, 256, 0, stream>>>(a1, W2t, dinv, hs2);
    k_agg2<<<G_AGG, 256, 0, stream>>>(hs2, offsets, csr, dinv, b2, out);
}

// Round 7
// 334.955 us; speedup vs baseline: 1.0741x; 1.0017x over previous
//
#include <hip/hip_runtime.h>
#include <hip/hip_bf16.h>

#define N_NODES 100000
#define N_EDGES 1600000
#define IN_FEAT 256
#define HID_F   128
#define OUT_FT  64

#define NBUK   256
#define NPB    391      // nodes per bucket: 256*391 = 100096 >= N
#define BUKCAP 8192     // mean 6250, sigma ~79 -> +24 sigma, safe
#define EPB    4096     // edges per bin block
#define G_BIN  ((N_EDGES + EPB - 1) / EPB)  // 391
#define G_GEMM ((N_NODES + 63) / 64)        // 1563, 64-row tiles
#define G_CAST ((IN_FEAT * HID_F + HID_F * OUT_FT + 255) / 256)  // 160
#define G_AGG  ((N_NODES + 7) / 8)          // 12500, 2 nodes per wave

typedef unsigned short u16;
typedef __attribute__((ext_vector_type(8))) unsigned short u16x8;
typedef __attribute__((ext_vector_type(8))) short short8;
typedef __attribute__((ext_vector_type(4))) float f32x4;

static __device__ inline u16 f2bf(float f) {
    __hip_bfloat16 h = __float2bfloat16(f);
    return *reinterpret_cast<u16*>(&h);
}
static __device__ inline float bf2f(u16 u) {
    union { unsigned u; float f; } c;
    c.u = ((unsigned)u) << 16;
    return c.f;
}

// ---------------- pass A: bin edges by dst bucket (+ weight cast piggyback) ----------------
// pairs entry is PACKED: (dstLocal << 17) | src   (dstLocal < 391 < 2^9, src < 100000 < 2^17)

__global__ __launch_bounds__(256) void k_bin(const int* __restrict__ srcA,
                                             const int* __restrict__ dstA,
                                             int* __restrict__ gcur, unsigned* __restrict__ pairs,
                                             const float* __restrict__ W1,
                                             const float* __restrict__ W2,
                                             u16* __restrict__ W1t, u16* __restrict__ W2t) {
    if (blockIdx.x >= G_BIN) {
        int idx = (blockIdx.x - G_BIN) * 256 + threadIdx.x;
        if (idx < IN_FEAT * HID_F) {
            int k = idx / HID_F, n = idx % HID_F;
            W1t[n * IN_FEAT + k] = f2bf(W1[idx]);
        } else {
            int e2 = idx - IN_FEAT * HID_F;
            if (e2 < HID_F * OUT_FT) {
                int k = e2 / OUT_FT, n = e2 % OUT_FT;
                W2t[n * HID_F + k] = f2bf(W2[e2]);
            }
        }
        return;
    }
    __shared__ int lh[NBUK];
    int t = threadIdx.x;
    int e0 = blockIdx.x * EPB;
    if (t < NBUK) lh[t] = 0;
    __syncthreads();
#pragma unroll
    for (int i = 0; i < EPB / 256; i++) {
        int e = e0 + i * 256 + t;
        if (e < N_EDGES) atomicAdd(&lh[dstA[e] / NPB], 1);
    }
    __syncthreads();
    if (t < NBUK) {
        int c = lh[t];
        lh[t] = atomicAdd(&gcur[t], c);  // becomes this block's base in bucket
    }
    __syncthreads();
#pragma unroll
    for (int i = 0; i < EPB / 256; i++) {
        int e = e0 + i * 256 + t;
        if (e < N_EDGES) {
            int d = dstA[e];
            int b = d / NPB;
            int p = atomicAdd(&lh[b], 1);
            if (p < BUKCAP) {
                unsigned packed = ((unsigned)(d - b * NPB) << 17) | (unsigned)srcA[e];
                pairs[(size_t)b * BUKCAP + p] = packed;
            }
        }
    }
}

// ---------------- pass B: per-bucket CSR fill + offsets + dinv (scan folded in) ----------------

__global__ __launch_bounds__(256) void k_fillB(const unsigned* __restrict__ pairs,
                                               const int* __restrict__ gcnt,
                                               int* __restrict__ offsets,
                                               float* __restrict__ dinv,
                                               int* __restrict__ csr) {
    __shared__ int hist[NPB];
    __shared__ int sm[256];
    __shared__ int s_ebase;
    int b = blockIdx.x, t = threadIdx.x;
    int nbase = b * NPB;
    int nn = min(NPB, N_NODES - nbase);

    // exclusive scan over bucket counts
    int gv = gcnt[t];
    sm[t] = gv;
    __syncthreads();
    for (int o = 1; o < 256; o <<= 1) {
        int u = (t >= o) ? sm[t - o] : 0;
        __syncthreads();
        sm[t] += u;
        __syncthreads();
    }
    if (t == b) s_ebase = sm[t] - gv;
    __syncthreads();
    int ebase = s_ebase;
    int cnt = gcnt[b];
    const unsigned* pb = pairs + (size_t)b * BUKCAP;

    for (int i = t; i < NPB; i += 256) hist[i] = 0;
    __syncthreads();
    for (int i = t; i < cnt; i += 256) atomicAdd(&hist[pb[i] >> 17], 1);
    __syncthreads();

    // exclusive scan over hist[0..nn): thread t owns nodes [2t, 2t+2)
    int base2 = t * 2;
    int c0 = (base2 < NPB) ? hist[base2] : 0;
    int c1 = (base2 + 1 < NPB) ? hist[base2 + 1] : 0;
    int s = c0 + c1;
    __syncthreads();
    sm[t] = s;
    __syncthreads();
    for (int o = 1; o < 256; o <<= 1) {
        int u = (t >= o) ? sm[t - o] : 0;
        __syncthreads();
        sm[t] += u;
        __syncthreads();
    }
    int run = ebase + sm[t] - s;
    __syncthreads();
    int cc[2] = {c0, c1};
#pragma unroll
    for (int q = 0; q < 2; q++) {
        int n = base2 + q;
        if (n < nn) {
            int g = nbase + n;
            offsets[g] = run;
            dinv[g] = rsqrtf((float)(cc[q] + 1));  // +1 self loop
            hist[n] = run;                          // becomes placement cursor
            run += cc[q];
        }
    }
    __syncthreads();
    for (int i = t; i < cnt; i += 256) {
        unsigned e = pb[i];
        int p = atomicAdd(&hist[e >> 17], 1);
        csr[p] = (int)(e & 0x1FFFFu);
    }
    if (b == NBUK - 1 && t == 0) offsets[N_NODES] = N_EDGES;
}

// ---------------- MFMA bf16 GEMM, layer 1 ----------------
// 64-row tiles, dbuf LDS, ONE barrier per k-step, 2-DEEP register pipeline:
// at iter s issue loads for s+2; write the s+1 set (issued a full iteration
// earlier) to LDS after the MFMAs -> HBM latency covered by a whole iteration.

__global__ __launch_bounds__(256) void k_gemm1(const float* __restrict__ A,
                                               const u16* __restrict__ Bt,
                                               const float* __restrict__ dinv,
                                               u16* __restrict__ C) {
    __shared__ u16 As[2][64][40];    // 10240 B
    __shared__ u16 Bs[2][128][40];   // 20480 B
    int tid = threadIdx.x;
    int wv = tid >> 6, lane = tid & 63;
    int m16 = lane & 15, quad = lane >> 4;
    int row0 = blockIdx.x * 64;

    int ar = tid >> 2, aq = tid & 3;
    int br = tid >> 1, bh = tid & 1;
    int arow_g = row0 + ar;
    if (arow_g >= N_NODES) arow_g = N_NODES - 1;   // clamp, stores guarded
    const float* ap = &A[(size_t)arow_g * IN_FEAT + aq * 8];
    const u16*   bp = &Bt[(size_t)br * IN_FEAT + bh * 16];

    f32x4 acc[8];
#pragma unroll
    for (int j = 0; j < 8; j++) acc[j] = (f32x4)(0.f);

    // prologue: stage step 0 directly; issue step 1 into reg set 1
    {
        f32x4 a0 = *(const f32x4*)&ap[0];
        f32x4 a1 = *(const f32x4*)&ap[4];
        u16x8 b0 = *(const u16x8*)&bp[0];
        u16x8 b1 = *(const u16x8*)&bp[8];
        u16x8 av;
#pragma unroll
        for (int j = 0; j < 4; j++) { av[j] = f2bf(a0[j]); av[4 + j] = f2bf(a1[j]); }
        *(u16x8*)&As[0][ar][aq * 8] = av;
        *(u16x8*)&Bs[0][br][bh * 16] = b0;
        *(u16x8*)&Bs[0][br][bh * 16 + 8] = b1;
    }
    f32x4 ra0[2], ra1[2]; u16x8 rb0[2], rb1[2];
    ra0[1] = *(const f32x4*)&ap[32];
    ra1[1] = *(const f32x4*)&ap[36];
    rb0[1] = *(const u16x8*)&bp[32];
    rb1[1] = *(const u16x8*)&bp[40];

#pragma unroll
    for (int s = 0; s < 8; s++) {
        const int buf = s & 1;
        if (s + 2 < 8) {               // issue loads for step s+2 (set buf is free)
            int k0 = (s + 2) * 32;
            ra0[buf] = *(const f32x4*)&ap[k0];
            ra1[buf] = *(const f32x4*)&ap[k0 + 4];
            rb0[buf] = *(const u16x8*)&bp[k0];
            rb1[buf] = *(const u16x8*)&bp[k0 + 8];
        }
        __syncthreads();   // LDS[buf] ready; LDS[buf^1] free to overwrite
        short8 af = *(const short8*)&As[buf][wv * 16 + m16][quad * 8];
#pragma unroll
        for (int ct = 0; ct < 8; ct++) {
            short8 bf = *(const short8*)&Bs[buf][16 * ct + m16][quad * 8];
            acc[ct] = __builtin_amdgcn_mfma_f32_16x16x32_bf16(af, bf, acc[ct], 0, 0, 0);
        }
        if (s + 1 < 8) {               // write step s+1 (issued at iter s-1)
            u16x8 av;
#pragma unroll
            for (int j = 0; j < 4; j++) {
                av[j] = f2bf(ra0[buf ^ 1][j]); av[4 + j] = f2bf(ra1[buf ^ 1][j]);
            }
            *(u16x8*)&As[buf ^ 1][ar][aq * 8] = av;
            *(u16x8*)&Bs[buf ^ 1][br][bh * 16] = rb0[buf ^ 1];
            *(u16x8*)&Bs[buf ^ 1][br][bh * 16 + 8] = rb1[buf ^ 1];
        }
    }

#pragma unroll
    for (int r4 = 0; r4 < 4; r4++) {
        int grow = row0 + wv * 16 + quad * 4 + r4;
        if (grow < N_NODES) {
            float dv = dinv[grow];
#pragma unroll
            for (int ct = 0; ct < 8; ct++)
                C[(size_t)grow * HID_F + 16 * ct + m16] = f2bf(acc[ct][r4] * dv);
        }
    }
}

// ---------------- MFMA bf16 GEMM, layer 2 ----------------
// Same 2-deep pipeline. K=128, 4 steps.

__global__ __launch_bounds__(256) void k_gemm2(const u16* __restrict__ A,
                                               const u16* __restrict__ Bt,
                                               const float* __restrict__ dinv,
                                               u16* __restrict__ C) {
    __shared__ u16 As[2][64][40];   // 10240 B
    __shared__ u16 Bs[2][64][40];   // 10240 B
    int tid = threadIdx.x;
    int wv = tid >> 6, lane = tid & 63;
    int m16 = lane & 15, quad = lane >> 4;
    int row0 = blockIdx.x * 64;

    int ar = tid >> 2, aq = tid & 3;   // A: row 0..63, 8-elem quarter
    int arow_g = row0 + ar;
    if (arow_g >= N_NODES) arow_g = N_NODES - 1;
    const u16* ap = &A[(size_t)arow_g * HID_F + aq * 8];
    const u16* bp = &Bt[(size_t)ar * HID_F + aq * 8];  // B: row 0..63, same quarter split

    f32x4 acc[4];
#pragma unroll
    for (int j = 0; j < 4; j++) acc[j] = (f32x4)(0.f);

    {
        u16x8 a0 = *(const u16x8*)&ap[0];
        u16x8 b0 = *(const u16x8*)&bp[0];
        *(u16x8*)&As[0][ar][aq * 8] = a0;
        *(u16x8*)&Bs[0][ar][aq * 8] = b0;
    }
    u16x8 rna[2], rnb[2];
    rna[1] = *(const u16x8*)&ap[32];
    rnb[1] = *(const u16x8*)&bp[32];

#pragma unroll
    for (int s = 0; s < 4; s++) {
        const int buf = s & 1;
        if (s + 2 < 4) {
            int k0 = (s + 2) * 32;
            rna[buf] = *(const u16x8*)&ap[k0];
            rnb[buf] = *(const u16x8*)&bp[k0];
        }
        __syncthreads();
        short8 af = *(const short8*)&As[buf][wv * 16 + m16][quad * 8];
#pragma unroll
        for (int ct = 0; ct < 4; ct++) {
            short8 bf = *(const short8*)&Bs[buf][16 * ct + m16][quad * 8];
            acc[ct] = __builtin_amdgcn_mfma_f32_16x16x32_bf16(af, bf, acc[ct], 0, 0, 0);
        }
        if (s + 1 < 4) {
            *(u16x8*)&As[buf ^ 1][ar][aq * 8] = rna[buf ^ 1];
            *(u16x8*)&Bs[buf ^ 1][ar][aq * 8] = rnb[buf ^ 1];
        }
    }

#pragma unroll
    for (int r4 = 0; r4 < 4; r4++) {
        int grow = row0 + wv * 16 + quad * 4 + r4;
        if (grow < N_NODES) {
            float dv = dinv[grow];
#pragma unroll
            for (int ct = 0; ct < 4; ct++)
                C[(size_t)grow * OUT_FT + 16 * ct + m16] = f2bf(acc[ct][r4] * dv);
        }
    }
}

// ---------------- aggregation: wide-gather CSR reduce ----------------
// agg1: 2 nodes per wave (half-wave each); 16 lanes x 16B cover a 256B row;
// main loop keeps 4 gathers in flight per lane (8 edges/node/iter).

__global__ __launch_bounds__(256) void k_agg1(const u16* __restrict__ hs,
                                              const int* __restrict__ offsets,
                                              const int* __restrict__ csr,
                                              const float* __restrict__ dinv,
                                              const float* __restrict__ b,
                                              u16* __restrict__ out) {
    int wave = threadIdx.x >> 6;
    int lane = threadIdx.x & 63;
    int half = lane >> 5;
    int node = blockIdx.x * 8 + wave * 2 + half;
    if (node >= N_NODES) return;
    int gl = lane & 31;
    int g = gl >> 4;          // edge slot 0..1 within this node's half-wave
    int fl = gl & 15;         // feature-block lane
    const int fo = fl * 8;    // 8 features per lane
    int beg = offsets[node], end = offsets[node + 1];

    float accA[8], accB[8];
#pragma unroll
    for (int i = 0; i < 8; i++) { accA[i] = 0.f; accB[i] = 0.f; }

    int j = beg;
    for (; j + 8 <= end; j += 8) {  // 8 edges, 4 gather loads in flight per lane
        int s0 = csr[j + g];
        int s1 = csr[j + 2 + g];
        int s2 = csr[j + 4 + g];
        int s3 = csr[j + 6 + g];
        u16x8 r0 = *(const u16x8*)&hs[(size_t)s0 * HID_F + fo];
        u16x8 r1 = *(const u16x8*)&hs[(size_t)s1 * HID_F + fo];
        u16x8 r2 = *(const u16x8*)&hs[(size_t)s2 * HID_F + fo];
        u16x8 r3 = *(const u16x8*)&hs[(size_t)s3 * HID_F + fo];
#pragma unroll
        for (int i = 0; i < 8; i++) {
            accA[i] += bf2f(r0[i]) + bf2f(r1[i]);
            accB[i] += bf2f(r2[i]) + bf2f(r3[i]);
        }
    }
    if (j + 4 <= end) {
        int s0 = csr[j + g];
        int s1 = csr[j + 2 + g];
        u16x8 r0 = *(const u16x8*)&hs[(size_t)s0 * HID_F + fo];
        u16x8 r1 = *(const u16x8*)&hs[(size_t)s1 * HID_F + fo];
#pragma unroll
        for (int i = 0; i < 8; i++) accA[i] += bf2f(r0[i]) + bf2f(r1[i]);
        j += 4;
    }
    for (; j < end; j += 2) {
        int idx = j + g;
        if (idx < end) {
            int s = csr[idx];
            u16x8 r0 = *(const u16x8*)&hs[(size_t)s * HID_F + fo];
#pragma unroll
            for (int i = 0; i < 8; i++) accB[i] += bf2f(r0[i]);
        }
    }
    // reduce the 2 edge slots (stays within this node's 32-lane half)
#pragma unroll
    for (int i = 0; i < 8; i++) {
        float v = accA[i] + accB[i];
        v += __shfl_xor(v, 16, 64);
        accA[i] = v;
    }
    if (g == 0) {
        u16x8 sr = *(const u16x8*)&hs[(size_t)node * HID_F + fo];
        float dv = dinv[node];
        f32x4 b0 = *(const f32x4*)&b[fo];
        f32x4 b1 = *(const f32x4*)&b[fo + 4];
        u16x8 o;
#pragma unroll
        for (int i = 0; i < 4; i++) {
            o[i]     = f2bf(fmaxf(dv * (accA[i]     + bf2f(sr[i]))     + b0[i], 0.f));
            o[4 + i] = f2bf(fmaxf(dv * (accA[4 + i] + bf2f(sr[4 + i])) + b1[i], 0.f));
        }
        *(u16x8*)&out[(size_t)node * HID_F + fo] = o;
    }
}

// agg2: 2 nodes per wave; 8 lanes x 16B cover a 128B row;
// main loop keeps 4 gathers in flight per lane (16 edges/node/iter); fp32 out.

__global__ __launch_bounds__(256) void k_agg2(const u16* __restrict__ hs,
                                              const int* __restrict__ offsets,
                                              const int* __restrict__ csr,
                                              const float* __restrict__ dinv,
                                              const float* __restrict__ b,
                                              float* __restrict__ out) {
    int wave = threadIdx.x >> 6;
    int lane = threadIdx.x & 63;
    int half = lane >> 5;
    int node = blockIdx.x * 8 + wave * 2 + half;
    if (node >= N_NODES) return;
    int gl = lane & 31;
    int g = gl >> 3;          // edge slot 0..3 within this node's half-wave
    int fl = gl & 7;          // feature-block lane
    const int fo = fl * 8;
    int beg = offsets[node], end = offsets[node + 1];

    float accA[8], accB[8];
#pragma unroll
    for (int i = 0; i < 8; i++) { accA[i] = 0.f; accB[i] = 0.f; }

    int j = beg;
    for (; j + 16 <= end; j += 16) {  // 16 edges, 4 gathers in flight per lane
        int s0 = csr[j + g];
        int s1 = csr[j + 4 + g];
        int s2 = csr[j + 8 + g];
        int s3 = csr[j + 12 + g];
        u16x8 r0 = *(const u16x8*)&hs[(size_t)s0 * OUT_FT + fo];
        u16x8 r1 = *(const u16x8*)&hs[(size_t)s1 * OUT_FT + fo];
        u16x8 r2 = *(const u16x8*)&hs[(size_t)s2 * OUT_FT + fo];
        u16x8 r3 = *(const u16x8*)&hs[(size_t)s3 * OUT_FT + fo];
#pragma unroll
        for (int i = 0; i < 8; i++) {
            accA[i] += bf2f(r0[i]) + bf2f(r1[i]);
            accB[i] += bf2f(r2[i]) + bf2f(r3[i]);
        }
    }
    if (j + 8 <= end) {
        int s0 = csr[j + g];
        int s1 = csr[j + 4 + g];
        u16x8 r0 = *(const u16x8*)&hs[(size_t)s0 * OUT_FT + fo];
        u16x8 r1 = *(const u16x8*)&hs[(size_t)s1 * OUT_FT + fo];
#pragma unroll
        for (int i = 0; i < 8; i++) accA[i] += bf2f(r0[i]) + bf2f(r1[i]);
        j += 8;
    }
    for (; j < end; j += 4) {
        int idx = j + g;
        if (idx < end) {
            int s = csr[idx];
            u16x8 r0 = *(const u16x8*)&hs[(size_t)s * OUT_FT + fo];
#pragma unroll
            for (int i = 0; i < 8; i++) accB[i] += bf2f(r0[i]);
        }
    }
#pragma unroll
    for (int i = 0; i < 8; i++) {
        float v = accA[i] + accB[i];
        v += __shfl_xor(v, 8, 64);
        v += __shfl_xor(v, 16, 64);
        accA[i] = v;
    }
    if (g == 0) {
        u16x8 sr = *(const u16x8*)&hs[(size_t)node * OUT_FT + fo];
        float dv = dinv[node];
        f32x4 b0 = *(const f32x4*)&b[fo];
        f32x4 b1 = *(const f32x4*)&b[fo + 4];
        f32x4 o0, o1;
#pragma unroll
        for (int i = 0; i < 4; i++) {
            o0[i] = dv * (accA[i]     + bf2f(sr[i]))     + b0[i];
            o1[i] = dv * (accA[4 + i] + bf2f(sr[4 + i])) + b1[i];
        }
        *(f32x4*)&out[(size_t)node * OUT_FT + fo] = o0;
        *(f32x4*)&out[(size_t)node * OUT_FT + fo + 4] = o1;
    }
}

// ---------------- launch ----------------

extern "C" void kernel_launch(void* const* d_in, const int* in_sizes, int n_in,
                              void* d_out, int out_size, void* d_ws, size_t ws_size,
                              hipStream_t stream) {
    const float* x  = (const float*)d_in[0];
    const int*   ei = (const int*)d_in[1];  // [2][E]
    const float* W1 = (const float*)d_in[2];
    const float* b1 = (const float*)d_in[3];
    const float* W2 = (const float*)d_in[4];
    const float* b2 = (const float*)d_in[5];
    float* out = (float*)d_out;

    char* ws = (char*)d_ws;
    int*   offsets = (int*)(ws + 0);          // (N+1) ints -> 400512
    float* dinv    = (float*)(ws + 400512);   // N floats   -> 800512
    int*   csr     = (int*)(ws + 800512);     // E ints     -> 7200512
    u16*   W1t     = (u16*)(ws + 7200512);    // 128x256    -> 7266048
    u16*   W2t     = (u16*)(ws + 7266048);    // 64x128     -> 7282432
    int*   gcur    = (int*)(ws + 7282432);    // 256 ints   -> 7283456
    u16*   hs1     = (u16*)(ws + 7284608);    // N*128 bf16 -> 32884608
    u16*   a1      = (u16*)(ws + 32884608);   // N*128 bf16 -> 58484608
    unsigned* pairs = (unsigned*)(ws + 32884608); // 8 MB packed, dead before agg1 writes a1
    u16*   hs2     = hs1;                     // hs1 dead after agg1

    const int* srcA = ei;
    const int* dstA = ei + N_EDGES;

    hipMemsetAsync(gcur, 0, NBUK * sizeof(int), stream);

    k_bin<<<G_BIN + G_CAST, 256, 0, stream>>>(srcA, dstA, gcur, pairs, W1, W2, W1t, W2t);
    k_fillB<<<NBUK, 256, 0, stream>>>(pairs, gcur, offsets, dinv, csr);

    k_gemm1<<<G_GEMM, 256, 0, stream>>>(x, W1t, dinv, hs1);
    k_agg1<<<G_AGG, 256, 0, stream>>>(hs1, offsets, csr, dinv, b1, a1);
    k_gemm2<<<G_GEMM, 256, 0, stream>>>(a1, W2t, dinv, hs2);
    k_agg2<<<G_AGG, 256, 0, stream>>>(hs2, offsets, csr, dinv, b2, out);
}

// Round 8
// 334.703 us; speedup vs baseline: 1.0749x; 1.0008x over previous
//
#include <hip/hip_runtime.h>
#include <hip/hip_bf16.h>

#define N_NODES 100000
#define N_EDGES 1600000
#define IN_FEAT 256
#define HID_F   128
#define OUT_FT  64

#define NBUK   256
#define NPB    391      // nodes per bucket: 256*391 = 100096 >= N
#define BUKCAP 8192     // mean 6250, sigma ~79 -> +24 sigma, safe
#define EPB    2048     // edges per bin block (halved: 782 blocks, ~3/CU)
#define G_BIN  ((N_EDGES + EPB - 1) / EPB)  // 782
#define G_GEMM ((N_NODES + 63) / 64)        // 1563, 64-row tiles
#define G_CAST ((IN_FEAT * HID_F + HID_F * OUT_FT + 255) / 256)  // 160
#define G_AGG  ((N_NODES + 7) / 8)          // 12500, 2 nodes per wave

typedef unsigned short u16;
typedef __attribute__((ext_vector_type(8))) unsigned short u16x8;
typedef __attribute__((ext_vector_type(8))) short short8;
typedef __attribute__((ext_vector_type(4))) float f32x4;

static __device__ inline u16 f2bf(float f) {
    __hip_bfloat16 h = __float2bfloat16(f);
    return *reinterpret_cast<u16*>(&h);
}
static __device__ inline float bf2f(u16 u) {
    union { unsigned u; float f; } c;
    c.u = ((unsigned)u) << 16;
    return c.f;
}

// ---------------- pass A: bin edges by dst bucket (+ weight cast piggyback) ----------------
// pairs entry is PACKED: (dstLocal << 17) | src   (dstLocal < 391 < 2^9, src < 100000 < 2^17)

__global__ __launch_bounds__(256) void k_bin(const int* __restrict__ srcA,
                                             const int* __restrict__ dstA,
                                             int* __restrict__ gcur, unsigned* __restrict__ pairs,
                                             const float* __restrict__ W1,
                                             const float* __restrict__ W2,
                                             u16* __restrict__ W1t, u16* __restrict__ W2t) {
    if (blockIdx.x >= G_BIN) {
        int idx = (blockIdx.x - G_BIN) * 256 + threadIdx.x;
        if (idx < IN_FEAT * HID_F) {
            int k = idx / HID_F, n = idx % HID_F;
            W1t[n * IN_FEAT + k] = f2bf(W1[idx]);
        } else {
            int e2 = idx - IN_FEAT * HID_F;
            if (e2 < HID_F * OUT_FT) {
                int k = e2 / OUT_FT, n = e2 % OUT_FT;
                W2t[n * HID_F + k] = f2bf(W2[e2]);
            }
        }
        return;
    }
    __shared__ int lh[NBUK];
    int t = threadIdx.x;
    int e0 = blockIdx.x * EPB;
    if (t < NBUK) lh[t] = 0;
    __syncthreads();
#pragma unroll
    for (int i = 0; i < EPB / 256; i++) {
        int e = e0 + i * 256 + t;
        if (e < N_EDGES) atomicAdd(&lh[dstA[e] / NPB], 1);
    }
    __syncthreads();
    if (t < NBUK) {
        int c = lh[t];
        lh[t] = atomicAdd(&gcur[t], c);  // becomes this block's base in bucket
    }
    __syncthreads();
#pragma unroll
    for (int i = 0; i < EPB / 256; i++) {
        int e = e0 + i * 256 + t;
        if (e < N_EDGES) {
            int d = dstA[e];
            int b = d / NPB;
            int p = atomicAdd(&lh[b], 1);
            if (p < BUKCAP) {
                unsigned packed = ((unsigned)(d - b * NPB) << 17) | (unsigned)srcA[e];
                pairs[(size_t)b * BUKCAP + p] = packed;
            }
        }
    }
}

// ---------------- pass B: per-bucket CSR fill + offsets + dinv ----------------
// 512 threads/block (8 waves/CU at 256 blocks): halves serial edge loops.

__global__ __launch_bounds__(512) void k_fillB(const unsigned* __restrict__ pairs,
                                               const int* __restrict__ gcnt,
                                               int* __restrict__ offsets,
                                               float* __restrict__ dinv,
                                               int* __restrict__ csr) {
    __shared__ int hist[NPB];
    __shared__ int sm[512];
    __shared__ int s_ebase;
    int b = blockIdx.x, t = threadIdx.x;   // t in [0,512)
    int nbase = b * NPB;
    int nn = min(NPB, N_NODES - nbase);

    // exclusive scan over 256 bucket counts (first 256 threads active per round)
    int gv = (t < NBUK) ? gcnt[t] : 0;
    if (t < NBUK) sm[t] = gv;
    __syncthreads();
    for (int o = 1; o < NBUK; o <<= 1) {
        int u = (t >= o && t < NBUK) ? sm[t - o] : 0;
        __syncthreads();
        if (t < NBUK) sm[t] += u;
        __syncthreads();
    }
    if (t == b) s_ebase = sm[t] - gv;
    __syncthreads();
    int ebase = s_ebase;
    int cnt = gcnt[b];
    const unsigned* pb = pairs + (size_t)b * BUKCAP;

    for (int i = t; i < NPB; i += 512) hist[i] = 0;
    __syncthreads();
    for (int i = t; i < cnt; i += 512) atomicAdd(&hist[pb[i] >> 17], 1);
    __syncthreads();

    // exclusive scan over hist[0..nn): one node per thread, width-512 scan
    int c0 = (t < NPB) ? hist[t] : 0;
    __syncthreads();
    sm[t] = c0;
    __syncthreads();
    for (int o = 1; o < 512; o <<= 1) {
        int u = (t >= o) ? sm[t - o] : 0;
        __syncthreads();
        sm[t] += u;
        __syncthreads();
    }
    int run = ebase + sm[t] - c0;   // exclusive prefix for node t
    __syncthreads();
    if (t < nn) {
        int g = nbase + t;
        offsets[g] = run;
        dinv[g] = rsqrtf((float)(c0 + 1));  // +1 self loop
        hist[t] = run;                       // becomes placement cursor
    }
    __syncthreads();
    for (int i = t; i < cnt; i += 512) {
        unsigned e = pb[i];
        int p = atomicAdd(&hist[e >> 17], 1);
        csr[p] = (int)(e & 0x1FFFFu);
    }
    if (b == NBUK - 1 && t == 0) offsets[N_NODES] = N_EDGES;
}

// ---------------- MFMA bf16 GEMM, layer 1 ----------------
// 64-row tiles, dbuf LDS, ONE barrier per k-step, 2-deep register pipeline.

__global__ __launch_bounds__(256) void k_gemm1(const float* __restrict__ A,
                                               const u16* __restrict__ Bt,
                                               const float* __restrict__ dinv,
                                               u16* __restrict__ C) {
    __shared__ u16 As[2][64][40];    // 10240 B
    __shared__ u16 Bs[2][128][40];   // 20480 B
    int tid = threadIdx.x;
    int wv = tid >> 6, lane = tid & 63;
    int m16 = lane & 15, quad = lane >> 4;
    int row0 = blockIdx.x * 64;

    int ar = tid >> 2, aq = tid & 3;
    int br = tid >> 1, bh = tid & 1;
    int arow_g = row0 + ar;
    if (arow_g >= N_NODES) arow_g = N_NODES - 1;   // clamp, stores guarded
    const float* ap = &A[(size_t)arow_g * IN_FEAT + aq * 8];
    const u16*   bp = &Bt[(size_t)br * IN_FEAT + bh * 16];

    f32x4 acc[8];
#pragma unroll
    for (int j = 0; j < 8; j++) acc[j] = (f32x4)(0.f);

    {
        f32x4 a0 = *(const f32x4*)&ap[0];
        f32x4 a1 = *(const f32x4*)&ap[4];
        u16x8 b0 = *(const u16x8*)&bp[0];
        u16x8 b1 = *(const u16x8*)&bp[8];
        u16x8 av;
#pragma unroll
        for (int j = 0; j < 4; j++) { av[j] = f2bf(a0[j]); av[4 + j] = f2bf(a1[j]); }
        *(u16x8*)&As[0][ar][aq * 8] = av;
        *(u16x8*)&Bs[0][br][bh * 16] = b0;
        *(u16x8*)&Bs[0][br][bh * 16 + 8] = b1;
    }
    f32x4 ra0[2], ra1[2]; u16x8 rb0[2], rb1[2];
    ra0[1] = *(const f32x4*)&ap[32];
    ra1[1] = *(const f32x4*)&ap[36];
    rb0[1] = *(const u16x8*)&bp[32];
    rb1[1] = *(const u16x8*)&bp[40];

#pragma unroll
    for (int s = 0; s < 8; s++) {
        const int buf = s & 1;
        if (s + 2 < 8) {               // issue loads for step s+2
            int k0 = (s + 2) * 32;
            ra0[buf] = *(const f32x4*)&ap[k0];
            ra1[buf] = *(const f32x4*)&ap[k0 + 4];
            rb0[buf] = *(const u16x8*)&bp[k0];
            rb1[buf] = *(const u16x8*)&bp[k0 + 8];
        }
        __syncthreads();
        short8 af = *(const short8*)&As[buf][wv * 16 + m16][quad * 8];
#pragma unroll
        for (int ct = 0; ct < 8; ct++) {
            short8 bf = *(const short8*)&Bs[buf][16 * ct + m16][quad * 8];
            acc[ct] = __builtin_amdgcn_mfma_f32_16x16x32_bf16(af, bf, acc[ct], 0, 0, 0);
        }
        if (s + 1 < 8) {
            u16x8 av;
#pragma unroll
            for (int j = 0; j < 4; j++) {
                av[j] = f2bf(ra0[buf ^ 1][j]); av[4 + j] = f2bf(ra1[buf ^ 1][j]);
            }
            *(u16x8*)&As[buf ^ 1][ar][aq * 8] = av;
            *(u16x8*)&Bs[buf ^ 1][br][bh * 16] = rb0[buf ^ 1];
            *(u16x8*)&Bs[buf ^ 1][br][bh * 16 + 8] = rb1[buf ^ 1];
        }
    }

#pragma unroll
    for (int r4 = 0; r4 < 4; r4++) {
        int grow = row0 + wv * 16 + quad * 4 + r4;
        if (grow < N_NODES) {
            float dv = dinv[grow];
#pragma unroll
            for (int ct = 0; ct < 8; ct++)
                C[(size_t)grow * HID_F + 16 * ct + m16] = f2bf(acc[ct][r4] * dv);
        }
    }
}

// ---------------- MFMA bf16 GEMM, layer 2 ----------------

__global__ __launch_bounds__(256) void k_gemm2(const u16* __restrict__ A,
                                               const u16* __restrict__ Bt,
                                               const float* __restrict__ dinv,
                                               u16* __restrict__ C) {
    __shared__ u16 As[2][64][40];   // 10240 B
    __shared__ u16 Bs[2][64][40];   // 10240 B
    int tid = threadIdx.x;
    int wv = tid >> 6, lane = tid & 63;
    int m16 = lane & 15, quad = lane >> 4;
    int row0 = blockIdx.x * 64;

    int ar = tid >> 2, aq = tid & 3;   // A: row 0..63, 8-elem quarter
    int arow_g = row0 + ar;
    if (arow_g >= N_NODES) arow_g = N_NODES - 1;
    const u16* ap = &A[(size_t)arow_g * HID_F + aq * 8];
    const u16* bp = &Bt[(size_t)ar * HID_F + aq * 8];  // B: row 0..63, same quarter split

    f32x4 acc[4];
#pragma unroll
    for (int j = 0; j < 4; j++) acc[j] = (f32x4)(0.f);

    {
        u16x8 a0 = *(const u16x8*)&ap[0];
        u16x8 b0 = *(const u16x8*)&bp[0];
        *(u16x8*)&As[0][ar][aq * 8] = a0;
        *(u16x8*)&Bs[0][ar][aq * 8] = b0;
    }
    u16x8 rna[2], rnb[2];
    rna[1] = *(const u16x8*)&ap[32];
    rnb[1] = *(const u16x8*)&bp[32];

#pragma unroll
    for (int s = 0; s < 4; s++) {
        const int buf = s & 1;
        if (s + 2 < 4) {
            int k0 = (s + 2) * 32;
            rna[buf] = *(const u16x8*)&ap[k0];
            rnb[buf] = *(const u16x8*)&bp[k0];
        }
        __syncthreads();
        short8 af = *(const short8*)&As[buf][wv * 16 + m16][quad * 8];
#pragma unroll
        for (int ct = 0; ct < 4; ct++) {
            short8 bf = *(const short8*)&Bs[buf][16 * ct + m16][quad * 8];
            acc[ct] = __builtin_amdgcn_mfma_f32_16x16x32_bf16(af, bf, acc[ct], 0, 0, 0);
        }
        if (s + 1 < 4) {
            *(u16x8*)&As[buf ^ 1][ar][aq * 8] = rna[buf ^ 1];
            *(u16x8*)&Bs[buf ^ 1][ar][aq * 8] = rnb[buf ^ 1];
        }
    }

#pragma unroll
    for (int r4 = 0; r4 < 4; r4++) {
        int grow = row0 + wv * 16 + quad * 4 + r4;
        if (grow < N_NODES) {
            float dv = dinv[grow];
#pragma unroll
            for (int ct = 0; ct < 4; ct++)
                C[(size_t)grow * OUT_FT + 16 * ct + m16] = f2bf(acc[ct][r4] * dv);
        }
    }
}

// ---------------- aggregation: wide-gather CSR reduce ----------------
// agg1: 2 nodes per wave (half-wave each); 16 lanes x 16B cover a 256B row;
// main loop keeps 4 gathers in flight per lane (8 edges/node/iter).

__global__ __launch_bounds__(256) void k_agg1(const u16* __restrict__ hs,
                                              const int* __restrict__ offsets,
                                              const int* __restrict__ csr,
                                              const float* __restrict__ dinv,
                                              const float* __restrict__ b,
                                              u16* __restrict__ out) {
    int wave = threadIdx.x >> 6;
    int lane = threadIdx.x & 63;
    int half = lane >> 5;
    int node = blockIdx.x * 8 + wave * 2 + half;
    if (node >= N_NODES) return;
    int gl = lane & 31;
    int g = gl >> 4;          // edge slot 0..1 within this node's half-wave
    int fl = gl & 15;         // feature-block lane
    const int fo = fl * 8;    // 8 features per lane
    int beg = offsets[node], end = offsets[node + 1];

    float accA[8], accB[8];
#pragma unroll
    for (int i = 0; i < 8; i++) { accA[i] = 0.f; accB[i] = 0.f; }

    int j = beg;
    for (; j + 8 <= end; j += 8) {  // 8 edges, 4 gather loads in flight per lane
        int s0 = csr[j + g];
        int s1 = csr[j + 2 + g];
        int s2 = csr[j + 4 + g];
        int s3 = csr[j + 6 + g];
        u16x8 r0 = *(const u16x8*)&hs[(size_t)s0 * HID_F + fo];
        u16x8 r1 = *(const u16x8*)&hs[(size_t)s1 * HID_F + fo];
        u16x8 r2 = *(const u16x8*)&hs[(size_t)s2 * HID_F + fo];
        u16x8 r3 = *(const u16x8*)&hs[(size_t)s3 * HID_F + fo];
#pragma unroll
        for (int i = 0; i < 8; i++) {
            accA[i] += bf2f(r0[i]) + bf2f(r1[i]);
            accB[i] += bf2f(r2[i]) + bf2f(r3[i]);
        }
    }
    if (j + 4 <= end) {
        int s0 = csr[j + g];
        int s1 = csr[j + 2 + g];
        u16x8 r0 = *(const u16x8*)&hs[(size_t)s0 * HID_F + fo];
        u16x8 r1 = *(const u16x8*)&hs[(size_t)s1 * HID_F + fo];
#pragma unroll
        for (int i = 0; i < 8; i++) accA[i] += bf2f(r0[i]) + bf2f(r1[i]);
        j += 4;
    }
    for (; j < end; j += 2) {
        int idx = j + g;
        if (idx < end) {
            int s = csr[idx];
            u16x8 r0 = *(const u16x8*)&hs[(size_t)s * HID_F + fo];
#pragma unroll
            for (int i = 0; i < 8; i++) accB[i] += bf2f(r0[i]);
        }
    }
    // reduce the 2 edge slots (stays within this node's 32-lane half)
#pragma unroll
    for (int i = 0; i < 8; i++) {
        float v = accA[i] + accB[i];
        v += __shfl_xor(v, 16, 64);
        accA[i] = v;
    }
    if (g == 0) {
        u16x8 sr = *(const u16x8*)&hs[(size_t)node * HID_F + fo];
        float dv = dinv[node];
        f32x4 b0 = *(const f32x4*)&b[fo];
        f32x4 b1 = *(const f32x4*)&b[fo + 4];
        u16x8 o;
#pragma unroll
        for (int i = 0; i < 4; i++) {
            o[i]     = f2bf(fmaxf(dv * (accA[i]     + bf2f(sr[i]))     + b0[i], 0.f));
            o[4 + i] = f2bf(fmaxf(dv * (accA[4 + i] + bf2f(sr[4 + i])) + b1[i], 0.f));
        }
        *(u16x8*)&out[(size_t)node * HID_F + fo] = o;
    }
}

// agg2: 2 nodes per wave; 8 lanes x 16B cover a 128B row;
// main loop keeps 4 gathers in flight per lane (16 edges/node/iter); fp32 out.

__global__ __launch_bounds__(256) void k_agg2(const u16* __restrict__ hs,
                                              const int* __restrict__ offsets,
                                              const int* __restrict__ csr,
                                              const float* __restrict__ dinv,
                                              const float* __restrict__ b,
                                              float* __restrict__ out) {
    int wave = threadIdx.x >> 6;
    int lane = threadIdx.x & 63;
    int half = lane >> 5;
    int node = blockIdx.x * 8 + wave * 2 + half;
    if (node >= N_NODES) return;
    int gl = lane & 31;
    int g = gl >> 3;          // edge slot 0..3 within this node's half-wave
    int fl = gl & 7;          // feature-block lane
    const int fo = fl * 8;
    int beg = offsets[node], end = offsets[node + 1];

    float accA[8], accB[8];
#pragma unroll
    for (int i = 0; i < 8; i++) { accA[i] = 0.f; accB[i] = 0.f; }

    int j = beg;
    for (; j + 16 <= end; j += 16) {  // 16 edges, 4 gathers in flight per lane
        int s0 = csr[j + g];
        int s1 = csr[j + 4 + g];
        int s2 = csr[j + 8 + g];
        int s3 = csr[j + 12 + g];
        u16x8 r0 = *(const u16x8*)&hs[(size_t)s0 * OUT_FT + fo];
        u16x8 r1 = *(const u16x8*)&hs[(size_t)s1 * OUT_FT + fo];
        u16x8 r2 = *(const u16x8*)&hs[(size_t)s2 * OUT_FT + fo];
        u16x8 r3 = *(const u16x8*)&hs[(size_t)s3 * OUT_FT + fo];
#pragma unroll
        for (int i = 0; i < 8; i++) {
            accA[i] += bf2f(r0[i]) + bf2f(r1[i]);
            accB[i] += bf2f(r2[i]) + bf2f(r3[i]);
        }
    }
    if (j + 8 <= end) {
        int s0 = csr[j + g];
        int s1 = csr[j + 4 + g];
        u16x8 r0 = *(const u16x8*)&hs[(size_t)s0 * OUT_FT + fo];
        u16x8 r1 = *(const u16x8*)&hs[(size_t)s1 * OUT_FT + fo];
#pragma unroll
        for (int i = 0; i < 8; i++) accA[i] += bf2f(r0[i]) + bf2f(r1[i]);
        j += 8;
    }
    for (; j < end; j += 4) {
        int idx = j + g;
        if (idx < end) {
            int s = csr[idx];
            u16x8 r0 = *(const u16x8*)&hs[(size_t)s * OUT_FT + fo];
#pragma unroll
            for (int i = 0; i < 8; i++) accB[i] += bf2f(r0[i]);
        }
    }
#pragma unroll
    for (int i = 0; i < 8; i++) {
        float v = accA[i] + accB[i];
        v += __shfl_xor(v, 8, 64);
        v += __shfl_xor(v, 16, 64);
        accA[i] = v;
    }
    if (g == 0) {
        u16x8 sr = *(const u16x8*)&hs[(size_t)node * OUT_FT + fo];
        float dv = dinv[node];
        f32x4 b0 = *(const f32x4*)&b[fo];
        f32x4 b1 = *(const f32x4*)&b[fo + 4];
        f32x4 o0, o1;
#pragma unroll
        for (int i = 0; i < 4; i++) {
            o0[i] = dv * (accA[i]     + bf2f(sr[i]))     + b0[i];
            o1[i] = dv * (accA[4 + i] + bf2f(sr[4 + i])) + b1[i];
        }
        *(f32x4*)&out[(size_t)node * OUT_FT + fo] = o0;
        *(f32x4*)&out[(size_t)node * OUT_FT + fo + 4] = o1;
    }
}

// ---------------- launch ----------------

extern "C" void kernel_launch(void* const* d_in, const int* in_sizes, int n_in,
                              void* d_out, int out_size, void* d_ws, size_t ws_size,
                              hipStream_t stream) {
    const float* x  = (const float*)d_in[0];
    const int*   ei = (const int*)d_in[1];  // [2][E]
    const float* W1 = (const float*)d_in[2];
    const float* b1 = (const float*)d_in[3];
    const float* W2 = (const float*)d_in[4];
    const float* b2 = (const float*)d_in[5];
    float* out = (float*)d_out;

    char* ws = (char*)d_ws;
    int*   offsets = (int*)(ws + 0);          // (N+1) ints -> 400512
    float* dinv    = (float*)(ws + 400512);   // N floats   -> 800512
    int*   csr     = (int*)(ws + 800512);     // E ints     -> 7200512
    u16*   W1t     = (u16*)(ws + 7200512);    // 128x256    -> 7266048
    u16*   W2t     = (u16*)(ws + 7266048);    // 64x128     -> 7282432
    int*   gcur    = (int*)(ws + 7282432);    // 256 ints   -> 7283456
    u16*   hs1     = (u16*)(ws + 7284608);    // N*128 bf16 -> 32884608
    u16*   a1      = (u16*)(ws + 32884608);   // N*128 bf16 -> 58484608
    unsigned* pairs = (unsigned*)(ws + 32884608); // 8 MB packed, dead before agg1 writes a1
    u16*   hs2     = hs1;                     // hs1 dead after agg1

    const int* srcA = ei;
    const int* dstA = ei + N_EDGES;

    hipMemsetAsync(gcur, 0, NBUK * sizeof(int), stream);

    k_bin<<<G_BIN + G_CAST, 256, 0, stream>>>(srcA, dstA, gcur, pairs, W1, W2, W1t, W2t);
    k_fillB<<<NBUK, 512, 0, stream>>>(pairs, gcur, offsets, dinv, csr);

    k_gemm1<<<G_GEMM, 256, 0, stream>>>(x, W1t, dinv, hs1);
    k_agg1<<<G_AGG, 256, 0, stream>>>(hs1, offsets, csr, dinv, b1, a1);
    k_gemm2<<<G_GEMM, 256, 0, stream>>>(a1, W2t, dinv, hs2);
    k_agg2<<<G_AGG, 256, 0, stream>>>(hs2, offsets, csr, dinv, b2, out);
}